// Round 12
// baseline (65.146 us; speedup 1.0000x reference)
//
#include <hip/hip_runtime.h>
#include <math.h>

// ---------------------------------------------------------------------------
// ConvLogicNetCIFAR forward. R12: megakernel with WAVE-UNIFORM channel
// ownership in the conv tower.
// R11 lesson: LDS conflicts (5M cyc) come from random-channel gathers across
// lanes (birthday collisions) -- padding can't fix them. Fix: one wave = one
// output channel at a time; lanes = spatial (pos-pair, py). Then all 8 tap
// bases are wave-uniform and a wave's 64 addresses are structured spatial
// offsets; odd ROW strides (35/19/11 dwords) spread banks to ~2-way (free).
//  - dup h2 cells: cell(r,c) = (v[r-1][c-1], v[r-1][c]); lane reads dwords
//    k and k+2 (ds_read2-fusable) = packed px values for two adjacent pw.
//  - orpool: py lives in lane bit0 -> one shfl_xor(1) + pk_max; the pooled
//    pair writes ONE aligned h2 + two straddle halves.
//  - stage4 keeps per-thread oc (1024 oc = 1024 thr); S4 aliases dead XB.
//  - LDS total ~157KB (XB 42.8K | S1 43.8K | S2 56.8K | S3 16K | red).
// 128 blocks x 1024 thr (cross-block split is dead: R8/R10 showed any
// agent-scope sync = per-XCD L2 flush; batch 128 < 256 CUs).
// Gate: c0 + c1*a + c2*b + c3*(a*b), c = softmax(w_row)@COEF.
// Conv tree quirk: off=2^lvl-1 -> level0 rows0..3, level1 rows1..2, level2 row3.
// ---------------------------------------------------------------------------

typedef _Float16 h16;
typedef _Float16 h2 __attribute__((ext_vector_type(2)));

__constant__ float c_coef_tbl[16][4] = {
    {0, 0, 0, 0}, {0, 0, 0, 1}, {0, 1, 0, -1}, {0, 1, 0, 0},
    {0, 0, 1, -1}, {0, 0, 1, 0}, {0, 1, 1, -2}, {0, 1, 1, -1},
    {1, -1, -1, 1}, {1, -1, -1, 2}, {1, 0, -1, 0}, {1, 0, -1, 1},
    {1, -1, 0, 0}, {1, -1, 0, 1}, {1, 0, 0, -1}, {1, 0, 0, 0}};

__device__ __forceinline__ float4 softmax_coef(const float* __restrict__ wr) {
  float m = -1e30f;
#pragma unroll
  for (int k = 0; k < 16; ++k) m = fmaxf(m, wr[k]);
  float e[16], s = 0.f;
#pragma unroll
  for (int k = 0; k < 16; ++k) { e[k] = __expf(wr[k] - m); s += e[k]; }
  float inv = 1.f / s;
  float c0 = 0.f, c1 = 0.f, c2 = 0.f, c3 = 0.f;
#pragma unroll
  for (int k = 0; k < 16; ++k) {
    c0 += e[k] * c_coef_tbl[k][0];
    c1 += e[k] * c_coef_tbl[k][1];
    c2 += e[k] * c_coef_tbl[k][2];
    c3 += e[k] * c_coef_tbl[k][3];
  }
  return make_float4(c0 * inv, c1 * inv, c2 * inv, c3 * inv);
}

__device__ __forceinline__ float gate_eval(float4 c, float a, float b) {
  return c.x + c.y * a + c.z * b + c.w * (a * b);
}
__device__ __forceinline__ float4 dec_cf(uint2 u) {
  h2 p0, p1;
  *(unsigned*)&p0 = u.x;
  *(unsigned*)&p1 = u.y;
  return make_float4((float)p0[0], (float)p0[1], (float)p1[0], (float)p1[1]);
}
__device__ __forceinline__ h2 gateh(const h2* c, h2 a, h2 b) {
  return c[0] + c[1] * a + c[2] * b + c[3] * (a * b);
}
__device__ __forceinline__ h2 tree8(const h2 (&ch)[4][4], const h2* lv) {
  h2 t0 = gateh(ch[0], lv[0], lv[1]);
  h2 t1 = gateh(ch[1], lv[2], lv[3]);
  h2 t2 = gateh(ch[2], lv[4], lv[5]);
  h2 t3 = gateh(ch[3], lv[6], lv[7]);
  h2 u0 = gateh(ch[1], t0, t1);
  h2 u1 = gateh(ch[2], t2, t3);
  return gateh(ch[3], u0, u1);
}
__device__ __forceinline__ h2 shfl1_h2(h2 v) {
  int a = __builtin_bit_cast(int, v);
  int b = __shfl_xor(a, 1, 64);
  return __builtin_bit_cast(h2, b);
}
__device__ __forceinline__ h2 pkmax(h2 a, h2 b) {
  h2 r;
  r[0] = a[0] > b[0] ? a[0] : b[0];
  r[1] = a[1] > b[1] ? a[1] : b[1];
  return r;
}

// prep: g<71680 FC tree (o=g/7, s=g%7 -> fp16 coefs mcoefh[o*28+s*4], u16
// midx16[o*8..]); g in [71680,78464) conv gate coefs float4
// (w1[0,128) w2[128,640) w3[640,2688) w4[2688,6784); gate gg -> row oc*7+(gg&3)).
__global__ void prep_all(const float* __restrict__ w1, const float* __restrict__ w2,
                         const float* __restrict__ w3, const float* __restrict__ w4,
                         const float* __restrict__ fw1, const float* __restrict__ fw2,
                         const float* __restrict__ fw3,
                         const int* __restrict__ ca1, const int* __restrict__ cb1,
                         const int* __restrict__ ca2, const int* __restrict__ cb2,
                         const int* __restrict__ ca3, const int* __restrict__ cb3,
                         float4* __restrict__ coefC,
                         unsigned short* __restrict__ midx16,
                         _Float16* __restrict__ mcoefh) {
  int g = blockIdx.x * blockDim.x + threadIdx.x;
  if (g < 71680) {
    int o = g / 7;
    int s = g - o * 7;
    float4 c;
    if (s < 4) {
      int k = (s < 2) ? ca3[o] : cb3[o];
      int j = (s & 1) ? cb2[k] : ca2[k];
      midx16[o * 8 + s * 2]     = (unsigned short)ca1[j];
      midx16[o * 8 + s * 2 + 1] = (unsigned short)cb1[j];
      c = softmax_coef(fw1 + j * 16);
    } else if (s < 6) {
      int k = (s == 4) ? ca3[o] : cb3[o];
      c = softmax_coef(fw2 + k * 16);
    } else {
      c = softmax_coef(fw3 + o * 16);
    }
    _Float16* mc = mcoefh + o * 28 + s * 4;
    mc[0] = (_Float16)c.x; mc[1] = (_Float16)c.y;
    mc[2] = (_Float16)c.z; mc[3] = (_Float16)c.w;
  } else if (g < 78464) {
    int gg = g - 71680;
    int base = gg;
    const float* w;
    if (gg < 128)       {             w = w1; }
    else if (gg < 640)  { gg -= 128;  w = w2; }
    else if (gg < 2688) { gg -= 640;  w = w3; }
    else                { gg -= 2688; w = w4; }
    coefC[base] = softmax_coef(w + ((gg >> 2) * 7 + (gg & 3)) * 16);
  }
}

// load one oc's taps (dword cell offsets) + coef splats
__device__ __forceinline__ void load_oc(const int* __restrict__ leaf,
                                        const float4* __restrict__ coef, int oc,
                                        int IPS, int IRS, int (&toff)[8],
                                        h2 (&ch)[4][4]) {
#pragma unroll
  for (int l = 0; l < 8; ++l) {
    int k = leaf[oc * 8 + l];
    int cc = k / 9;
    int p = k - 9 * cc;
    int di = p / 3;
    int dj = p - 3 * di;
    toff[l] = cc * IPS + di * IRS + dj;
  }
#pragma unroll
  for (int r = 0; r < 4; ++r) {
    float4 c = coef[oc * 4 + r];
    _Float16 x0 = (_Float16)c.x, x1 = (_Float16)c.y,
             x2 = (_Float16)c.z, x3 = (_Float16)c.w;
    ch[r][0][0] = x0; ch[r][0][1] = x0;
    ch[r][1][0] = x1; ch[r][1][1] = x1;
    ch[r][2][0] = x2; ch[r][2][1] = x2;
    ch[r][3][0] = x3; ch[r][3][1] = x3;
  }
}

// Megakernel: one block per batch element, 128 blocks x 1024 threads.
__global__ __launch_bounds__(1024) void mega(
    const float* __restrict__ x, const float4* __restrict__ coefC,
    const int* __restrict__ l1, const int* __restrict__ l2,
    const int* __restrict__ l3, const int* __restrict__ l4,
    const unsigned short* __restrict__ midx16,
    const _Float16* __restrict__ mcoefh, float* __restrict__ out) {
  // dup h2 regions; odd ROW strides (35/19/11) for bank spread.
  __shared__ __align__(16) h2 XB[9 * 1190];    // [9][34 rows][35]   42,840B
  __shared__ __align__(16) h2 S1[32 * 342];    // [32][18][19]       43,776B
  __shared__ __align__(16) h2 S2[128 * 111];   // [128][10][11]+1pad 56,832B
  __shared__ __align__(16) h16 S3[512 * 16];   // plain [512][4][4]  16,384B
  __shared__ float red[16][10];
  h16* S4h = (h16*)XB;  // stage4 out aliases dead XB (4096 h16 = 8KB)

  int tid = threadIdx.x;
  int b = blockIdx.x;
  int wave = tid >> 6, lane = tid & 63;
  int py = lane & 1, halfl = lane >> 1;

  // ---- phase 0: zero S1/S2 + binarize x -> XB dup-padded ----
  {
    float4* z1 = (float4*)S1;  // 10944 dwords = 2736 float4
    float4* z2 = (float4*)S2;  // 14208 dwords = 3552 float4
    float4 zz = make_float4(0.f, 0.f, 0.f, 0.f);
    for (int i = tid; i < 2736; i += 1024) z1[i] = zz;
    for (int i = tid; i < 3552; i += 1024) z2[i] = zz;
  }
  const float* xg = x + b * 3072;
  for (int cell = tid; cell < 10710; cell += 1024) {
    int c9 = cell / 1190;
    int rem = cell - c9 * 1190;
    int r = rem / 35, cj = rem - 35 * r;
    int th = c9 / 3, c = c9 - 3 * th;
    float thr = (float)(th + 1) * 0.25f;
    _Float16 lo = (_Float16)0, hi = (_Float16)0;
    if (r >= 1 && r <= 32 && cj <= 34) {
      const float* row = xg + c * 1024 + (r - 1) * 32;
      if (cj >= 1 && cj <= 32) lo = (_Float16)((row[cj - 1] > thr) ? 1.f : 0.f);
      if (cj <= 31)            hi = (_Float16)((row[cj] > thr) ? 1.f : 0.f);
    }
    XB[cell] = h2{lo, hi};
  }
  __syncthreads();

  // ---- stage 1: XB[9][34][35] -> S1[32][18][19]; 2 ocs/wave, 4 iters ----
#pragma unroll
  for (int k = 0; k < 2; ++k) {
    int oc = wave + 16 * k;
    int toff[8]; h2 ch[4][4];
    load_oc(l1, coefC, oc, 1190, 35, toff, ch);
#pragma unroll
    for (int it = 0; it < 4; ++it) {
      int pairIdx = it * 32 + halfl;          // 0..127
      int pwp = pairIdx & 7, ph = pairIdx >> 3;
      int base = (2 * ph + py) * 35 + 4 * pwp;
      h2 A[8], B[8];
#pragma unroll
      for (int l = 0; l < 8; ++l) { int a0 = toff[l] + base; A[l] = XB[a0]; B[l] = XB[a0 + 2]; }
      h2 oA = tree8(ch, A), oB = tree8(ch, B);
      h2 pA = pkmax(oA, shfl1_h2(oA));
      h2 pB = pkmax(oB, shfl1_h2(oB));
      _Float16 vA = pA[0] > pA[1] ? pA[0] : pA[1];
      _Float16 vB = pB[0] > pB[1] ? pB[0] : pB[1];
      if (py == 0) {
        int rowc = oc * 342 + (ph + 1) * 19 + 2 * pwp;  // even col cell
        S1[rowc + 1] = h2{vA, vB};                      // full odd col
        h16* s1h = (h16*)S1;
        s1h[2 * rowc + 1] = vA;                         // hi of even col
        s1h[2 * (rowc + 2)] = vB;                       // lo of next even col
      }
    }
  }
  __syncthreads();

  // ---- stage 2: S1 -> S2[128][10][11]; 8 ocs/wave, 1 iter each ----
  {
    int pwp = halfl & 3, ph = halfl >> 2;     // halfl 0..31
    int base = (2 * ph + py) * 19 + 4 * pwp;
#pragma unroll
    for (int k = 0; k < 8; ++k) {
      int oc = wave + 16 * k;
      int toff[8]; h2 ch[4][4];
      load_oc(l2, coefC + 128, oc, 342, 19, toff, ch);
      h2 A[8], B[8];
#pragma unroll
      for (int l = 0; l < 8; ++l) { int a0 = toff[l] + base; A[l] = S1[a0]; B[l] = S1[a0 + 2]; }
      h2 oA = tree8(ch, A), oB = tree8(ch, B);
      h2 pA = pkmax(oA, shfl1_h2(oA));
      h2 pB = pkmax(oB, shfl1_h2(oB));
      _Float16 vA = pA[0] > pA[1] ? pA[0] : pA[1];
      _Float16 vB = pB[0] > pB[1] ? pB[0] : pB[1];
      if (py == 0) {
        int rowc = oc * 111 + (ph + 1) * 11 + 2 * pwp;
        S2[rowc + 1] = h2{vA, vB};
        h16* s2h = (h16*)S2;
        s2h[2 * rowc + 1] = vA;
        s2h[2 * (rowc + 2)] = vB;
      }
    }
  }
  __syncthreads();

  // ---- stage 3: S2 -> S3 plain [512][16]; 4 ocs/wave-iter, 8 iters ----
  {
    int q = lane >> 4, ll = lane & 15;
    int py3 = ll & 1;
    int pairIdx = ll >> 1;                    // 0..7
    int pwp = pairIdx & 1, ph = pairIdx >> 1; // ph 0..3
    int base = (2 * ph + py3) * 11 + 4 * pwp;
#pragma unroll
    for (int it = 0; it < 8; ++it) {
      int oc = it * 64 + wave * 4 + q;
      int toff[8]; h2 ch[4][4];
      load_oc(l3, coefC + 640, oc, 111, 11, toff, ch);
      h2 A[8], B[8];
#pragma unroll
      for (int l = 0; l < 8; ++l) { int a0 = toff[l] + base; A[l] = S2[a0]; B[l] = S2[a0 + 2]; }
      h2 oA = tree8(ch, A), oB = tree8(ch, B);
      h2 pA = pkmax(oA, shfl1_h2(oA));
      h2 pB = pkmax(oB, shfl1_h2(oB));
      _Float16 vA = pA[0] > pA[1] ? pA[0] : pA[1];
      _Float16 vB = pB[0] > pB[1] ? pB[0] : pB[1];
      if (py3 == 0) {
        // positions (ph, 2pwp), (ph, 2pwp+1): h16 idx even -> one h2 store
        ((h2*)S3)[(oc * 16 + ph * 4 + 2 * pwp) >> 1] = h2{vA, vB};
      }
    }
  }
  __syncthreads();

  // ---- stage 4: plain in [512][4][4], 1 thread/oc, bounds-checked ----
  {
    int oc = tid;
    int cc[8], di[8], dj[8];
#pragma unroll
    for (int l = 0; l < 8; ++l) {
      int k = l4[oc * 8 + l];
      cc[l] = k / 9;
      int p = k - 9 * cc[l];
      di[l] = p / 3;
      dj[l] = p - 3 * di[l];
    }
    float4 c0 = coefC[2688 + oc * 4 + 0];
    float4 c1 = coefC[2688 + oc * 4 + 1];
    float4 c2 = coefC[2688 + oc * 4 + 2];
    float4 c3 = coefC[2688 + oc * 4 + 3];
#pragma unroll
    for (int pos = 0; pos < 4; ++pos) {
      int pw = pos & 1, ph = pos >> 1;
      float best = -1e30f;
#pragma unroll
      for (int pyy = 0; pyy < 2; ++pyy) {
#pragma unroll
        for (int px = 0; px < 2; ++px) {
          int i = 2 * ph + pyy, j = 2 * pw + px;
          float lv[8];
#pragma unroll
          for (int l = 0; l < 8; ++l) {
            int ii = i + di[l] - 1, jj = j + dj[l] - 1;
            float v = 0.f;
            if ((unsigned)ii < 4u && (unsigned)jj < 4u)
              v = (float)S3[cc[l] * 16 + ii * 4 + jj];
            lv[l] = v;
          }
          float t0 = gate_eval(c0, lv[0], lv[1]);
          float t1 = gate_eval(c1, lv[2], lv[3]);
          float t2 = gate_eval(c2, lv[4], lv[5]);
          float t3 = gate_eval(c3, lv[6], lv[7]);
          float u0 = gate_eval(c1, t0, t1);
          float u1 = gate_eval(c2, t2, t3);
          best = fmaxf(best, gate_eval(c3, u0, u1));
        }
      }
      S4h[oc * 4 + pos] = (h16)best;
    }
  }
  __syncthreads();

  // ---- fused FC, streamed; o = k*1024 + tid ----
  const uint4* mi = (const uint4*)midx16;
  const uint2* mc = (const uint2*)mcoefh;
  int wid = tid >> 6;
#pragma unroll
  for (int k = 0; k < 10; ++k) {
    int o = k * 1024 + tid;
    uint4 I = mi[o];
    const uint2* cfp = mc + o * 7;
    float L0 = gate_eval(dec_cf(cfp[0]), (float)S4h[I.x & 0xffff], (float)S4h[I.x >> 16]);
    float L1 = gate_eval(dec_cf(cfp[1]), (float)S4h[I.y & 0xffff], (float)S4h[I.y >> 16]);
    float L2 = gate_eval(dec_cf(cfp[2]), (float)S4h[I.z & 0xffff], (float)S4h[I.z >> 16]);
    float L3 = gate_eval(dec_cf(cfp[3]), (float)S4h[I.w & 0xffff], (float)S4h[I.w >> 16]);
    float M0 = gate_eval(dec_cf(cfp[4]), L0, L1);
    float M1 = gate_eval(dec_cf(cfp[5]), L2, L3);
    float y = gate_eval(dec_cf(cfp[6]), M0, M1);
#pragma unroll
    for (int m = 32; m > 0; m >>= 1) y += __shfl_xor(y, m, 64);
    if ((tid & 63) == 0) red[wid][k] = y;
  }
  __syncthreads();
  if (tid < 10) {
    float s = 0.f;
#pragma unroll
    for (int w = 0; w < 16; ++w) s += red[w][tid];
    out[b * 10 + tid] = s * 0.1f;
  }
}

extern "C" void kernel_launch(void* const* d_in, const int* in_sizes, int n_in,
                              void* d_out, int out_size, void* d_ws, size_t ws_size,
                              hipStream_t stream) {
  const float* x   = (const float*)d_in[0];
  const float* w1  = (const float*)d_in[1];
  const float* w2  = (const float*)d_in[2];
  const float* w3  = (const float*)d_in[3];
  const float* w4  = (const float*)d_in[4];
  const float* fw1 = (const float*)d_in[5];
  const float* fw2 = (const float*)d_in[6];
  const float* fw3 = (const float*)d_in[7];
  const int* l1  = (const int*)d_in[8];
  const int* l2  = (const int*)d_in[9];
  const int* l3  = (const int*)d_in[10];
  const int* l4  = (const int*)d_in[11];
  const int* ca1 = (const int*)d_in[12];
  const int* cb1 = (const int*)d_in[13];
  const int* ca2 = (const int*)d_in[14];
  const int* cb2 = (const int*)d_in[15];
  const int* ca3 = (const int*)d_in[16];
  const int* cb3 = (const int*)d_in[17];

  char* ws = (char*)d_ws;
  float4*         coefC  = (float4*)ws;                      // 108,544 B
  unsigned short* midx16 = (unsigned short*)(ws + 108544);   // 163,840 B
  _Float16*       mcoefh = (_Float16*)(ws + 108544 + 163840);// 573,440 B

  prep_all<<<307, 256, 0, stream>>>(w1, w2, w3, w4, fw1, fw2, fw3,
                                    ca1, cb1, ca2, cb2, ca3, cb3,
                                    coefC, midx16, mcoefh);
  mega<<<128, 1024, 0, stream>>>(x, coefC, l1, l2, l3, l4, midx16, mcoefh,
                                 (float*)d_out);
}